// Round 1
// baseline (7136.582 us; speedup 1.0000x reference)
//
#include <hip/hip_runtime.h>

// out = x + Ax + A^2 x + A^3 x  (COO SpMM via atomic scatter)
// N=100000 nodes, D=100 features, E=1600000 edges, layer_num=3 (fixed by setup_inputs)

#define NODES 100000
#define DIM 100
#define DIM4 25   // float4 chunks per row (400 B, 16B-aligned)

// 32 threads per edge; lanes 0..24 each handle one float4 of the row.
__global__ void spmm_scatter(const int* __restrict__ rows,
                             const int* __restrict__ cols,
                             const float* __restrict__ vals,
                             const float* __restrict__ x,
                             float* __restrict__ y,
                             int E) {
    long long gid = (long long)blockIdx.x * blockDim.x + threadIdx.x;
    int e    = (int)(gid >> 5);
    int lane = (int)(gid & 31);
    if (e >= E || lane >= DIM4) return;
    int   r = rows[e];
    int   c = cols[e];
    float v = vals[e];
    const float4* xr = (const float4*)(x + (size_t)c * DIM);
    float4 m = xr[lane];
    float* yr = y + (size_t)r * DIM + (size_t)lane * 4;
    unsafeAtomicAdd(yr + 0, v * m.x);
    unsafeAtomicAdd(yr + 1, v * m.y);
    unsafeAtomicAdd(yr + 2, v * m.z);
    unsafeAtomicAdd(yr + 3, v * m.w);
}

// out[i] += h[i], float4-vectorized
__global__ void add_inplace(float* __restrict__ out, const float* __restrict__ h, int n4) {
    int i = blockIdx.x * blockDim.x + threadIdx.x;
    if (i < n4) {
        float4 a = ((const float4*)out)[i];
        float4 b = ((const float4*)h)[i];
        a.x += b.x; a.y += b.y; a.z += b.z; a.w += b.w;
        ((float4*)out)[i] = a;
    }
}

extern "C" void kernel_launch(void* const* d_in, const int* in_sizes, int n_in,
                              void* d_out, int out_size, void* d_ws, size_t ws_size,
                              hipStream_t stream) {
    const float* emb  = (const float*)d_in[0];
    const int*   rows = (const int*)  d_in[1];
    const int*   cols = (const int*)  d_in[2];
    const float* vals = (const float*)d_in[3];
    const int E = in_sizes[1];

    const size_t nd = (size_t)NODES * DIM;           // 10M floats
    float* hA = (float*)d_ws;
    float* hB = hA + nd;

    float* out = (float*)d_out;

    // acc = embedding
    hipMemcpyAsync(out, emb, nd * sizeof(float), hipMemcpyDeviceToDevice, stream);

    const int n4 = (int)(nd / 4);
    dim3 addGrid((n4 + 255) / 256);
    dim3 addBlock(256);
    // 32 threads per edge, 8 edges per 256-thread block
    dim3 scatGrid((unsigned)(((long long)E * 32 + 255) / 256));
    dim3 scatBlock(256);

    const float* cur = emb;
    float* bufs[2] = {hA, hB};
    for (int l = 0; l < 3; ++l) {
        float* h = bufs[l & 1];
        hipMemsetAsync(h, 0, nd * sizeof(float), stream);
        spmm_scatter<<<scatGrid, scatBlock, 0, stream>>>(rows, cols, vals, cur, h, E);
        add_inplace<<<addGrid, addBlock, 0, stream>>>(out, h, n4);
        cur = h;
    }
}

// Round 2
// 648.338 us; speedup vs baseline: 11.0075x; 11.0075x over previous
//
#include <hip/hip_runtime.h>

// out = x + Ax + A^2 x + A^3 x  (COO -> CSR build per call, then pull-based gather SpMM)
// N=100000, D=100, E=1600000, layer_num=3 (fixed by setup_inputs)

#define NODES 100000
#define DIM 100
#define DIM4 25                       // float4 chunks per row (400 B)
#define SCAN_BLK 256
#define NBLK ((NODES + SCAN_BLK - 1) / SCAN_BLK)   // 391
#define NPAD (NBLK * SCAN_BLK)                     // 100096 (entries >= NODES scan to E)

__global__ void hist_kernel(const int* __restrict__ rows, int* __restrict__ counts, int E) {
    int e = blockIdx.x * blockDim.x + threadIdx.x;
    if (e < E) atomicAdd(&counts[rows[e]], 1);
}

// in-place per-block exclusive scan; emits block totals
__global__ void scan1_kernel(int* __restrict__ data, int* __restrict__ blocksums, int n) {
    __shared__ int s[SCAN_BLK];
    int gid = blockIdx.x * SCAN_BLK + threadIdx.x;
    int v = (gid < n) ? data[gid] : 0;
    s[threadIdx.x] = v;
    __syncthreads();
    for (int off = 1; off < SCAN_BLK; off <<= 1) {
        int t = (threadIdx.x >= off) ? s[threadIdx.x - off] : 0;
        __syncthreads();
        s[threadIdx.x] += t;
        __syncthreads();
    }
    data[gid] = s[threadIdx.x] - v;                 // exclusive
    if (threadIdx.x == SCAN_BLK - 1) blocksums[blockIdx.x] = s[SCAN_BLK - 1];
}

// single-block exclusive scan of the 391 block totals
__global__ void scan2_kernel(int* __restrict__ bs, int nb) {
    __shared__ int s[512];
    int v = ((int)threadIdx.x < nb) ? bs[threadIdx.x] : 0;
    s[threadIdx.x] = v;
    __syncthreads();
    for (int off = 1; off < 512; off <<= 1) {
        int t = ((int)threadIdx.x >= off) ? s[threadIdx.x - off] : 0;
        __syncthreads();
        s[threadIdx.x] += t;
        __syncthreads();
    }
    if ((int)threadIdx.x < nb) bs[threadIdx.x] = s[threadIdx.x] - v;
}

__global__ void scan3_kernel(int* __restrict__ data, const int* __restrict__ bs) {
    int gid = blockIdx.x * SCAN_BLK + threadIdx.x;
    data[gid] += bs[blockIdx.x];
}

// place each edge at its CSR slot: interleaved (col, val-bits) record
__global__ void scatter_kernel(const int* __restrict__ rows, const int* __restrict__ cols,
                               const float* __restrict__ vals,
                               int* __restrict__ cursor, int2* __restrict__ csr, int E) {
    int e = blockIdx.x * blockDim.x + threadIdx.x;
    if (e < E) {
        int r = rows[e];
        int pos = atomicAdd(&cursor[r], 1);
        int2 rec;
        rec.x = cols[e];
        rec.y = __float_as_int(vals[e]);
        csr[pos] = rec;
    }
}

// pull SpMM: 32 lanes per row, lanes 0..24 each own one float4 chunk.
// h (optional) gets the hop result; out gets (init ? x_chunk + acc : out + acc).
__global__ void gather_kernel(const int* __restrict__ rowstart,
                              const int2* __restrict__ csr,
                              const float* __restrict__ x,
                              float* __restrict__ h,
                              float* __restrict__ out,
                              int init) {
    int gid = blockIdx.x * blockDim.x + threadIdx.x;
    int row  = gid >> 5;
    int lane = gid & 31;
    if (row >= NODES || lane >= DIM4) return;
    int start = rowstart[row];
    int end   = rowstart[row + 1];
    const float4* x4 = (const float4*)x;
    float4 acc = make_float4(0.f, 0.f, 0.f, 0.f);
    for (int i = start; i < end; ++i) {
        int2 rec = csr[i];                              // broadcast across the 25 lanes
        float v  = __int_as_float(rec.y);
        float4 xv = x4[(size_t)rec.x * DIM4 + lane];    // 400 B coalesced row gather
        acc.x += v * xv.x; acc.y += v * xv.y; acc.z += v * xv.z; acc.w += v * xv.w;
    }
    size_t idx = (size_t)row * DIM4 + lane;
    if (h) ((float4*)h)[idx] = acc;
    float4 o;
    if (init) {
        float4 xo = x4[idx];
        o.x = xo.x + acc.x; o.y = xo.y + acc.y; o.z = xo.z + acc.z; o.w = xo.w + acc.w;
    } else {
        o = ((float4*)out)[idx];
        o.x += acc.x; o.y += acc.y; o.z += acc.z; o.w += acc.w;
    }
    ((float4*)out)[idx] = o;
}

extern "C" void kernel_launch(void* const* d_in, const int* in_sizes, int n_in,
                              void* d_out, int out_size, void* d_ws, size_t ws_size,
                              hipStream_t stream) {
    const float* emb  = (const float*)d_in[0];
    const int*   rows = (const int*)  d_in[1];
    const int*   cols = (const int*)  d_in[2];
    const float* vals = (const float*)d_in[3];
    const int E = in_sizes[1];

    const size_t nd_bytes = (size_t)NODES * DIM * sizeof(float);  // 40 MB

    char* w = (char*)d_ws;
    float* hA       = (float*)w;  w += nd_bytes;
    float* hB       = (float*)w;  w += nd_bytes;
    int2*  csr      = (int2*) w;  w += (size_t)E * sizeof(int2);  // 12.8 MB
    int*   rowstart = (int*)  w;  w += (size_t)NPAD * sizeof(int);
    int*   cursor   = (int*)  w;  w += (size_t)NPAD * sizeof(int);
    int*   bsums    = (int*)  w;  w += 512 * sizeof(int);
    // total ~93.6 MB

    float* out = (float*)d_out;

    // ---- build CSR (counting sort by row) ----
    hipMemsetAsync(rowstart, 0, (size_t)NPAD * sizeof(int), stream);
    hist_kernel<<<(E + 255) / 256, 256, 0, stream>>>(rows, rowstart, E);
    scan1_kernel<<<NBLK, SCAN_BLK, 0, stream>>>(rowstart, bsums, NODES);
    scan2_kernel<<<1, 512, 0, stream>>>(bsums, NBLK);
    scan3_kernel<<<NBLK, SCAN_BLK, 0, stream>>>(rowstart, bsums);
    hipMemcpyAsync(cursor, rowstart, (size_t)NPAD * sizeof(int),
                   hipMemcpyDeviceToDevice, stream);
    scatter_kernel<<<(E + 255) / 256, 256, 0, stream>>>(rows, cols, vals, cursor, csr, E);

    // ---- 3 gather SpMM layers, accumulation fused ----
    const int threads = NODES * 32;
    dim3 gGrid((threads + 255) / 256), gBlock(256);
    gather_kernel<<<gGrid, gBlock, 0, stream>>>(rowstart, csr, emb, hA, out, 1);
    gather_kernel<<<gGrid, gBlock, 0, stream>>>(rowstart, csr, hA, hB, out, 0);
    gather_kernel<<<gGrid, gBlock, 0, stream>>>(rowstart, csr, hB, (float*)nullptr, out, 0);
}

// Round 3
// 526.673 us; speedup vs baseline: 13.5503x; 1.2310x over previous
//
#include <hip/hip_runtime.h>

// out = x + Ax + A^2 x + A^3 x  (COO -> CSR per call; pull gather SpMM with fp16 operand)
// N=100000, D=100, E=1600000, layer_num=3 (fixed by setup_inputs)

#define NODES 100000
#define DIM 100
#define DIM4 25                       // 4-feature chunks per row
#define SCAN_BLK 256
#define NBLK ((NODES + SCAN_BLK - 1) / SCAN_BLK)   // 391
#define NPAD (NBLK * SCAN_BLK)                     // 100096

typedef _Float16 half4_t __attribute__((ext_vector_type(4)));

__global__ void hist_kernel(const int* __restrict__ rows, int* __restrict__ counts, int E) {
    int e = blockIdx.x * blockDim.x + threadIdx.x;
    if (e < E) atomicAdd(&counts[rows[e]], 1);
}

__global__ void scan1_kernel(int* __restrict__ data, int* __restrict__ blocksums, int n) {
    __shared__ int s[SCAN_BLK];
    int gid = blockIdx.x * SCAN_BLK + threadIdx.x;
    int v = (gid < n) ? data[gid] : 0;
    s[threadIdx.x] = v;
    __syncthreads();
    for (int off = 1; off < SCAN_BLK; off <<= 1) {
        int t = (threadIdx.x >= off) ? s[threadIdx.x - off] : 0;
        __syncthreads();
        s[threadIdx.x] += t;
        __syncthreads();
    }
    data[gid] = s[threadIdx.x] - v;                 // exclusive
    if (threadIdx.x == SCAN_BLK - 1) blocksums[blockIdx.x] = s[SCAN_BLK - 1];
}

__global__ void scan2_kernel(int* __restrict__ bs, int nb) {
    __shared__ int s[512];
    int v = ((int)threadIdx.x < nb) ? bs[threadIdx.x] : 0;
    s[threadIdx.x] = v;
    __syncthreads();
    for (int off = 1; off < 512; off <<= 1) {
        int t = ((int)threadIdx.x >= off) ? s[threadIdx.x - off] : 0;
        __syncthreads();
        s[threadIdx.x] += t;
        __syncthreads();
    }
    if ((int)threadIdx.x < nb) bs[threadIdx.x] = s[threadIdx.x] - v;
}

// finalize scan AND initialize the scatter cursor (replaces the d2d memcpy)
__global__ void scan3_kernel(int* __restrict__ data, int* __restrict__ cursor,
                             const int* __restrict__ bs) {
    int gid = blockIdx.x * SCAN_BLK + threadIdx.x;
    int v = data[gid] + bs[blockIdx.x];
    data[gid] = v;
    cursor[gid] = v;
}

__global__ void scatter_kernel(const int* __restrict__ rows, const int* __restrict__ cols,
                               const float* __restrict__ vals,
                               int* __restrict__ cursor, int2* __restrict__ csr, int E) {
    int e = blockIdx.x * blockDim.x + threadIdx.x;
    if (e < E) {
        int r = rows[e];
        int pos = atomicAdd(&cursor[r], 1);
        int2 rec;
        rec.x = cols[e];
        rec.y = __float_as_int(vals[e]);
        csr[pos] = rec;
    }
}

// fp32 [N*D] -> fp16 [N*D]
__global__ void cvt_kernel(const float4* __restrict__ src, half4_t* __restrict__ dst, int n4) {
    int i = blockIdx.x * blockDim.x + threadIdx.x;
    if (i < n4) {
        float4 f = src[i];
        half4_t h;
        h.x = (_Float16)f.x; h.y = (_Float16)f.y; h.z = (_Float16)f.z; h.w = (_Float16)f.w;
        dst[i] = h;
    }
}

// pull SpMM: 32 lanes per row, lanes 0..24 each own 4 features (8 B fp16 chunk).
// out = (init_src ? init_src[idx] : out[idx]) + acc ; h (optional) = fp16(acc)
__global__ void gather_kernel(const int* __restrict__ rowstart,
                              const int2* __restrict__ csr,
                              const half4_t* __restrict__ x,
                              const float4* __restrict__ init_src,
                              half4_t* __restrict__ h,
                              float4* __restrict__ out) {
    int gid = blockIdx.x * blockDim.x + threadIdx.x;
    int row  = gid >> 5;
    int lane = gid & 31;
    if (row >= NODES || lane >= DIM4) return;
    int start = rowstart[row];
    int end   = rowstart[row + 1];
    float4 acc = make_float4(0.f, 0.f, 0.f, 0.f);
    int i = start;
    for (; i + 1 < end; i += 2) {                   // 2x unroll: two gathers in flight
        int2 r0 = csr[i];
        int2 r1 = csr[i + 1];
        half4_t a = x[(size_t)r0.x * DIM4 + lane];
        half4_t b = x[(size_t)r1.x * DIM4 + lane];
        float v0 = __int_as_float(r0.y);
        float v1 = __int_as_float(r1.y);
        acc.x += v0 * (float)a.x + v1 * (float)b.x;
        acc.y += v0 * (float)a.y + v1 * (float)b.y;
        acc.z += v0 * (float)a.z + v1 * (float)b.z;
        acc.w += v0 * (float)a.w + v1 * (float)b.w;
    }
    if (i < end) {
        int2 r0 = csr[i];
        half4_t a = x[(size_t)r0.x * DIM4 + lane];
        float v0 = __int_as_float(r0.y);
        acc.x += v0 * (float)a.x;
        acc.y += v0 * (float)a.y;
        acc.z += v0 * (float)a.z;
        acc.w += v0 * (float)a.w;
    }
    size_t idx = (size_t)row * DIM4 + lane;
    if (h) {
        half4_t hv;
        hv.x = (_Float16)acc.x; hv.y = (_Float16)acc.y;
        hv.z = (_Float16)acc.z; hv.w = (_Float16)acc.w;
        h[idx] = hv;
    }
    float4 o = init_src ? init_src[idx] : out[idx];
    o.x += acc.x; o.y += acc.y; o.z += acc.z; o.w += acc.w;
    out[idx] = o;
}

extern "C" void kernel_launch(void* const* d_in, const int* in_sizes, int n_in,
                              void* d_out, int out_size, void* d_ws, size_t ws_size,
                              hipStream_t stream) {
    const float* emb  = (const float*)d_in[0];
    const int*   rows = (const int*)  d_in[1];
    const int*   cols = (const int*)  d_in[2];
    const float* vals = (const float*)d_in[3];
    const int E = in_sizes[1];

    const size_t nd   = (size_t)NODES * DIM;               // 10M elements
    const size_t nd_h = nd * sizeof(_Float16);             // 20 MB

    char* w = (char*)d_ws;
    half4_t* x0       = (half4_t*)w;  w += nd_h;
    half4_t* h1       = (half4_t*)w;  w += nd_h;
    half4_t* h2       = (half4_t*)w;  w += nd_h;
    int2*    csr      = (int2*)   w;  w += (size_t)E * sizeof(int2);   // 12.8 MB
    int*     rowstart = (int*)    w;  w += (size_t)NPAD * sizeof(int);
    int*     cursor   = (int*)    w;  w += (size_t)NPAD * sizeof(int);
    int*     bsums    = (int*)    w;  w += 512 * sizeof(int);

    float4* out = (float4*)d_out;

    // ---- build CSR (counting sort by row) + fp16 conversion ----
    hipMemsetAsync(rowstart, 0, (size_t)NPAD * sizeof(int), stream);
    const int n4 = (int)(nd / 4);                          // 2.5M
    cvt_kernel<<<(n4 + 255) / 256, 256, 0, stream>>>((const float4*)emb, x0, n4);
    hist_kernel<<<(E + 255) / 256, 256, 0, stream>>>(rows, rowstart, E);
    scan1_kernel<<<NBLK, SCAN_BLK, 0, stream>>>(rowstart, bsums, NODES);
    scan2_kernel<<<1, 512, 0, stream>>>(bsums, NBLK);
    scan3_kernel<<<NBLK, SCAN_BLK, 0, stream>>>(rowstart, cursor, bsums);
    scatter_kernel<<<(E + 255) / 256, 256, 0, stream>>>(rows, cols, vals, cursor, csr, E);

    // ---- 3 gather SpMM layers, accumulation fused ----
    const long long threads = (long long)NODES * 32;
    dim3 gGrid((unsigned)((threads + 255) / 256)), gBlock(256);
    gather_kernel<<<gGrid, gBlock, 0, stream>>>(rowstart, csr, x0, (const float4*)emb, h1, out);
    gather_kernel<<<gGrid, gBlock, 0, stream>>>(rowstart, csr, h1, (const float4*)nullptr, h2, out);
    gather_kernel<<<gGrid, gBlock, 0, stream>>>(rowstart, csr, h2, (const float4*)nullptr, (half4_t*)nullptr, out);
}